// Round 5
// baseline (464.295 us; speedup 1.0000x reference)
//
#include <hip/hip_runtime.h>
#include <hip/hip_bf16.h>

typedef __bf16 bf16x8 __attribute__((ext_vector_type(8)));
typedef __bf16 bf16x4 __attribute__((ext_vector_type(4)));
typedef float  f32x4  __attribute__((ext_vector_type(4)));

// tanh(x) = 1 - 2/(exp(2x)+1); native v_exp + v_rcp (no IEEE div expansion).
__device__ __forceinline__ float fast_tanh(float x) {
    float e = __expf(2.0f * x);
    float r = __builtin_amdgcn_rcpf(e + 1.0f);
    return __builtin_fmaf(-2.0f, r, 1.0f);
}

// Convert fp32 weights to bf16, TRANSPOSED to [n][k]: each lane's MFMA
// A-operand fragment (8 consecutive k at fixed n) is one contiguous 16B load.
__global__ void prep_weights(const float* __restrict__ W1,
                             const float* __restrict__ W2,
                             const float* __restrict__ W3,
                             __bf16* __restrict__ w1t,   // [256][64]
                             __bf16* __restrict__ w2t,   // [256][256]
                             __bf16* __restrict__ w3t) { // [64][256]
    int idx = blockIdx.x * blockDim.x + threadIdx.x;
    if (idx < 64 * 256) {                 // W1 [k=64][n=256] -> W1T[n][k]
        int n = idx >> 6, k = idx & 63;
        w1t[idx] = (__bf16)W1[k * 256 + n];
    }
    int i2 = idx - 64 * 256;
    if (i2 >= 0 && i2 < 256 * 256) {      // W2 [k=256][n=256] -> W2T[n][k]
        int n = i2 >> 8, k = i2 & 255;
        w2t[i2] = (__bf16)W2[k * 256 + n];
    }
    int i3 = idx - 64 * 256 - 256 * 256;  // W3 [k=256][n=64] -> W3T[n][k]
    if (i3 >= 0 && i3 < 64 * 256) {
        int n = i3 >> 8, k = i3 & 255;
        w3t[i3] = (__bf16)W3[k * 64 + n];
    }
}

// One block = 16 batch rows for ALL time steps. 1024 threads = 16 waves
// => 4 waves/SIMD interleaving inside every phase (was 2). Same total work:
// each wave owns an n-slice of 16 in GEMM1/GEMM2.
// OPERAND-SWAPPED MFMA: A = weight (W^T[n][k]), B = activation (h[m][k]).
// x-state lives in PERSISTENT REGISTERS of waves 0-3 (the GEMM3 D-fragment
// layout: lane(c,q) holds x[row=c][col=wave*16+q*4..+3]); trajectory is
// stored straight from registers. No xs array, no store phase.
__global__ __launch_bounds__(1024, 4)
void ode_kernel(const float* __restrict__ x0,
                const float* __restrict__ b1,
                const float* __restrict__ b2,
                const float* __restrict__ b3,
                const float* __restrict__ dt_scale,
                const int*   __restrict__ num_steps,
                const __bf16* __restrict__ w1t,
                const __bf16* __restrict__ w2t,
                const __bf16* __restrict__ w3t,
                float* __restrict__ out) {
    __shared__ __bf16 xb[16][72];                   // bf16 state; 144B stride, clean banks
    __shared__ __align__(16) __bf16 h1[16 * 256];   // XOR-swizzled, 512B row stride
    __shared__ __align__(16) __bf16 h2[16 * 256];

    const int tid  = threadIdx.x;
    const int wave = tid >> 6;       // 0..15
    const int lane = tid & 63;
    const int q    = lane >> 4;      // quad
    const int c    = lane & 15;      // n for A-frag(weight), m(batch row) for B-frag & D
    const int cx8  = (c & 7) << 3;   // h1/h2 swizzle term (element units)
    const int row0 = blockIdx.x * 16;

    const float scale = dt_scale[0] * 0.01f;   // dt_scale * DT
    const int   nT    = num_steps[0];

    const int nw = wave * 16 + c;    // this wave's output column (n) for G1/G2

    // ---- one-time weight fragment loads (A-operand layout, [n][k]) ----
    bf16x8 w1f[2];
    #pragma unroll
    for (int kt = 0; kt < 2; ++kt)
        w1f[kt] = *(const bf16x8*)(w1t + nw * 64 + kt * 32 + q * 8);
    bf16x8 w2f[8];
    #pragma unroll
    for (int kt = 0; kt < 8; ++kt)
        w2f[kt] = *(const bf16x8*)(w2t + nw * 256 + kt * 32 + q * 8);

    f32x4 b1v = *(const f32x4*)(b1 + wave * 16 + q * 4);
    f32x4 b2v = *(const f32x4*)(b2 + wave * 16 + q * 4);

    // ---- waves 0-3: GEMM3 weights + persistent x-state registers ----
    bf16x8 w3f[8];
    f32x4  b3v = (f32x4){0.f, 0.f, 0.f, 0.f};
    f32x4  xv  = (f32x4){0.f, 0.f, 0.f, 0.f};
    float* outp = out;
    if (wave < 4) {
        #pragma unroll
        for (int kt = 0; kt < 8; ++kt)
            w3f[kt] = *(const bf16x8*)(w3t + nw * 256 + kt * 32 + q * 8);
        b3v = *(const f32x4*)(b3 + wave * 16 + q * 4);
        // x0 slice: lane(c,q) owns x[row=c][col=wave*16+q*4..+3]
        xv = *(const f32x4*)(x0 + (size_t)(row0 + c) * 64 + wave * 16 + q * 4);
        outp = out + (size_t)(row0 + c) * 201 * 64 + wave * 16 + q * 4;
        *(f32x4*)outp = xv;              // t = 0 trajectory slice
        outp += 64;
        bf16x4 xbv;
        #pragma unroll
        for (int r = 0; r < 4; ++r) xbv[r] = (__bf16)xv[r];
        *(bf16x4*)(&xb[c][wave * 16 + q * 4]) = xbv;
    }
    __syncthreads();

    for (int t = 0; t < nT; ++t) {
        // ---- GEMM1: h1 = tanh(x @ W1 + b1); each wave: n-slice of 16 ----
        {
            f32x4 acc = b1v;
            #pragma unroll
            for (int kt = 0; kt < 2; ++kt) {
                bf16x8 a = *(const bf16x8*)(&xb[c][kt * 32 + q * 8]);
                acc = __builtin_amdgcn_mfma_f32_16x16x32_bf16(w1f[kt], a, acc, 0, 0, 0);
            }
            bf16x4 o;
            #pragma unroll
            for (int r = 0; r < 4; ++r) o[r] = (__bf16)fast_tanh(acc[r]);
            *(bf16x4*)(&h1[c * 256 + ((wave * 16 + q * 4) ^ cx8)]) = o;
        }
        __syncthreads();

        // ---- GEMM2: h2 = tanh(h1 @ W2 + b2); two 4-deep acc chains ----
        {
            f32x4 acc  = b2v;
            f32x4 accB = (f32x4){0, 0, 0, 0};
            #pragma unroll
            for (int kt = 0; kt < 4; ++kt) {
                bf16x8 a0 = *(const bf16x8*)(&h1[c * 256 + ((kt * 32 + q * 8) ^ cx8)]);
                bf16x8 a1 = *(const bf16x8*)(&h1[c * 256 + (((kt + 4) * 32 + q * 8) ^ cx8)]);
                acc  = __builtin_amdgcn_mfma_f32_16x16x32_bf16(w2f[kt],     a0, acc,  0, 0, 0);
                accB = __builtin_amdgcn_mfma_f32_16x16x32_bf16(w2f[kt + 4], a1, accB, 0, 0, 0);
            }
            f32x4 s = acc + accB;
            bf16x4 o;
            #pragma unroll
            for (int r = 0; r < 4; ++r) o[r] = (__bf16)fast_tanh(s[r]);
            *(bf16x4*)(&h2[c * 256 + ((wave * 16 + q * 4) ^ cx8)]) = o;
        }
        __syncthreads();

        // ---- GEMM3 (waves 0-3, one per SIMD): dx = h2 @ W3 + b3;
        //      x += dx*scale in registers; write xb + trajectory ----
        if (wave < 4) {
            f32x4 acc  = b3v;
            f32x4 accB = (f32x4){0, 0, 0, 0};
            #pragma unroll
            for (int kt = 0; kt < 4; ++kt) {
                bf16x8 a0 = *(const bf16x8*)(&h2[c * 256 + ((kt * 32 + q * 8) ^ cx8)]);
                bf16x8 a1 = *(const bf16x8*)(&h2[c * 256 + (((kt + 4) * 32 + q * 8) ^ cx8)]);
                acc  = __builtin_amdgcn_mfma_f32_16x16x32_bf16(w3f[kt],     a0, acc,  0, 0, 0);
                accB = __builtin_amdgcn_mfma_f32_16x16x32_bf16(w3f[kt + 4], a1, accB, 0, 0, 0);
            }
            acc += accB;
            xv += acc * scale;
            bf16x4 xbv;
            #pragma unroll
            for (int r = 0; r < 4; ++r) xbv[r] = (__bf16)xv[r];
            *(bf16x4*)(&xb[c][wave * 16 + q * 4]) = xbv;
            *(f32x4*)outp = xv;          // trajectory slice t+1
            outp += 64;
        }
        __syncthreads();   // fences xb for next GEMM1
    }
}

extern "C" void kernel_launch(void* const* d_in, const int* in_sizes, int n_in,
                              void* d_out, int out_size, void* d_ws, size_t ws_size,
                              hipStream_t stream) {
    const float* x0 = (const float*)d_in[0];
    const float* W1 = (const float*)d_in[1];
    const float* b1 = (const float*)d_in[2];
    const float* W2 = (const float*)d_in[3];
    const float* b2 = (const float*)d_in[4];
    const float* W3 = (const float*)d_in[5];
    const float* b3 = (const float*)d_in[6];
    const float* dt = (const float*)d_in[7];
    const int*   ns = (const int*)d_in[8];

    __bf16* w1t = (__bf16*)d_ws;           // 16384 bf16
    __bf16* w2t = w1t + 64 * 256;          // 65536 bf16
    __bf16* w3t = w2t + 256 * 256;         // 16384 bf16

    prep_weights<<<384, 256, 0, stream>>>(W1, W2, W3, w1t, w2t, w3t);

    int rows = in_sizes[0] / 64;           // 4096
    ode_kernel<<<rows / 16, 1024, 0, stream>>>(x0, b1, b2, b3, dt, ns,
                                               w1t, w2t, w3t, (float*)d_out);
}